// Round 10
// baseline (10369.513 us; speedup 1.0000x reference)
//
#include <hip/hip_runtime.h>
#include <hip/hip_bf16.h>

#define Bd 64
#define Td 64
#define Sd 128
#define Hd 512
#define Ed 256
#define Vd 10000
#define NBLK 256

// LDS weight offsets (floats)
#define W0IH 0      // 6*768
#define W0HH 4608   // 6*512
#define W1IH 7680   // 6*512
#define W1HH 10752  // 6*512
#define WTOT 13824

__device__ __forceinline__ float fast_tanh(float x) {
  float e = __expf(-2.0f * fabsf(x));
  float r = (1.0f - e) / (1.0f + e);
  return copysignf(r, x);
}
__device__ __forceinline__ float fast_sigmoid(float x) {
  return 1.0f / (1.0f + __expf(-x));
}
__device__ __forceinline__ float bf2f(unsigned short u) {
  return __uint_as_float(((unsigned int)u) << 16);
}

// software grid barrier: RELAXED spins + one release fence before arrive,
// one acquire fence at exit (r8: the 2.7x fix).
__device__ __forceinline__ void gbar(int* arrive, int* go, int ep, int blk, int tid) {
  __syncthreads();
  if (tid == 0) {
    __builtin_amdgcn_fence(__ATOMIC_RELEASE, "agent");
    __hip_atomic_store(&arrive[blk], ep, __ATOMIC_RELAXED, __HIP_MEMORY_SCOPE_AGENT);
  }
  if (blk == 0) {
    if (tid < NBLK) {
      while (__hip_atomic_load(&arrive[tid], __ATOMIC_RELAXED,
                               __HIP_MEMORY_SCOPE_AGENT) < ep) {
        __builtin_amdgcn_s_sleep(1);
      }
    }
    __syncthreads();
    if (tid == 0)
      __hip_atomic_store(go, ep, __ATOMIC_RELAXED, __HIP_MEMORY_SCOPE_AGENT);
  }
  if (tid == 0) {
    while (__hip_atomic_load(go, __ATOMIC_RELAXED, __HIP_MEMORY_SCOPE_AGENT) < ep) {
      __builtin_amdgcn_s_sleep(1);
    }
    __builtin_amdgcn_fence(__ATOMIC_ACQUIRE, "agent");
  }
  __syncthreads();
}

// C[M,N] = A[M,K] @ W[N,K]^T (+bias). SWAP: out row m=(t*64+b) -> (b*T+t).
template <bool SWAP, bool BIAS, bool OB>
__global__ void k_gemm_abt(const float* __restrict__ A, const float* __restrict__ W,
                           const float* __restrict__ bias, void* __restrict__ Cv,
                           int M, int N, int K) {
  __shared__ __align__(16) float As[16][64];
  __shared__ __align__(16) float Ws[16][64];
  int m0 = blockIdx.x * 64, n0 = blockIdx.y * 64;
  int tid = threadIdx.x;
  int tx = tid & 15, ty = tid >> 4;
  float acc[4][4] = {};
  for (int k0 = 0; k0 < K; k0 += 16) {
#pragma unroll
    for (int i = 0; i < 4; i++) {
      int e = tid + i * 256;
      int r = e >> 4, c = e & 15;
      As[c][r] = A[(long)(m0 + r) * K + k0 + c];
    }
#pragma unroll
    for (int i = 0; i < 4; i++) {
      int e = tid + i * 256;
      int r = e >> 4, c = e & 15;
      int n = n0 + r;
      Ws[c][r] = (n < N) ? W[(long)n * K + k0 + c] : 0.0f;
    }
    __syncthreads();
#pragma unroll
    for (int k = 0; k < 16; k++) {
      float a_[4], w_[4];
#pragma unroll
      for (int i = 0; i < 4; i++) a_[i] = As[k][ty * 4 + i];
#pragma unroll
      for (int j = 0; j < 4; j++) w_[j] = Ws[k][tx * 4 + j];
#pragma unroll
      for (int i = 0; i < 4; i++)
#pragma unroll
        for (int j = 0; j < 4; j++) acc[i][j] += a_[i] * w_[j];
    }
    __syncthreads();
  }
#pragma unroll
  for (int i = 0; i < 4; i++) {
    int m = m0 + ty * 4 + i;
#pragma unroll
    for (int j = 0; j < 4; j++) {
      int n = n0 + tx * 4 + j;
      if (n < N) {
        float v = acc[i][j];
        if (BIAS) v += bias[n];
        long idx;
        if (SWAP) {
          int t_ = m >> 6, b_ = m & 63;
          idx = ((long)(b_ * Td + t_)) * N + n;
        } else {
          idx = (long)m * N + n;
        }
        if (OB) {
          __hip_bfloat16 h = __float2bfloat16(v);
          ((unsigned short*)Cv)[idx] = *(unsigned short*)&h;
        } else {
          ((float*)Cv)[idx] = v;
        }
      }
    }
  }
}

// elementwise f32 -> bf16 copy
__global__ void k_tobf(const float* __restrict__ src, unsigned short* __restrict__ dst,
                       long n) {
  long i = (long)blockIdx.x * 1024 + threadIdx.x;
  if (i < n) {
    __hip_bfloat16 h = __float2bfloat16(src[i]);
    dst[i] = *(unsigned short*)&h;
  }
}

// embTf[t][e][b] = emb[x[b][t]][e]  (f32)
__global__ void k_embT(const int* __restrict__ x, const float* __restrict__ emb,
                       float* __restrict__ embTf) {
  __shared__ int rows[64];
  int t = blockIdx.x;
  if (threadIdx.x < 64) rows[threadIdx.x] = x[threadIdx.x * Td + t];
  __syncthreads();
  int e = threadIdx.x;
  for (int b = 0; b < 64; b++) {
    embTf[((long)t * Ed + e) * 64 + b] = emb[(long)rows[b] * Ed + e];
  }
}

// GRU cell phase, 16 waves; float4 weight reads + deep unroll for 32 loads in
// flight. Waves 0-5: ih(ctx) row-dots; 6-11: hh; 12-14 (C0): emb part.
template <bool C0>
__device__ __forceinline__ void cell_phase(
    int blk, int tid, int t, const float* __restrict__ aT,
    const float* __restrict__ embTf, const float* __restrict__ hT,
    const float* wIH, const float* wHH, const float* __restrict__ bih,
    const float* __restrict__ bhh, const float* __restrict__ dscale,
    float* __restrict__ houtT, float* __restrict__ ys, float* scratch) {
  int lane = tid & 63;
  int w = tid >> 6;
  const int RIH = C0 ? 768 : 512;
  float* ps = scratch;         // [12][64]
  float* psE = scratch + 768;  // [6][64]
  if (w < 6) {
    const float* wr = wIH + w * RIH;
    float acc = 0.f;
#pragma unroll 8
    for (int k = 0; k < 512; k += 4) {
      float4 w4 = *(const float4*)&wr[k];
      acc += aT[(k + 0) * 64 + lane] * w4.x + aT[(k + 1) * 64 + lane] * w4.y +
             aT[(k + 2) * 64 + lane] * w4.z + aT[(k + 3) * 64 + lane] * w4.w;
    }
    if (C0) acc = acc / dscale[lane];  // normalize softmax denominator
    ps[w * 64 + lane] = acc;
  } else if (w < 12) {
    const float* vr = wHH + (w - 6) * 512;
    float acc = 0.f;
#pragma unroll 8
    for (int k = 0; k < 512; k += 4) {
      float4 w4 = *(const float4*)&vr[k];
      acc += hT[(k + 0) * 64 + lane] * w4.x + hT[(k + 1) * 64 + lane] * w4.y +
             hT[(k + 2) * 64 + lane] * w4.z + hT[(k + 3) * 64 + lane] * w4.w;
    }
    ps[w * 64 + lane] = acc;
  } else if (C0 && w < 15) {
    int r0 = (w - 12) * 2;
    const float* w0 = wIH + r0 * 768 + 512;
    const float* w1 = wIH + (r0 + 1) * 768 + 512;
    const float* ef = embTf + (size_t)t * Ed * 64;
    float a0 = 0.f, a1 = 0.f;
#pragma unroll 8
    for (int e = 0; e < 256; e += 4) {
      float4 x0 = *(const float4*)&w0[e];
      float4 x1 = *(const float4*)&w1[e];
      float v0 = ef[(e + 0) * 64 + lane];
      float v1 = ef[(e + 1) * 64 + lane];
      float v2 = ef[(e + 2) * 64 + lane];
      float v3 = ef[(e + 3) * 64 + lane];
      a0 += v0 * x0.x + v1 * x0.y + v2 * x0.z + v3 * x0.w;
      a1 += v0 * x1.x + v1 * x1.y + v2 * x1.z + v3 * x1.w;
    }
    psE[r0 * 64 + lane] = a0;
    psE[(r0 + 1) * 64 + lane] = a1;
  }
  __syncthreads();
  if (tid < 128) {
    int jl = tid >> 6, b = tid & 63;
    float ir = ps[(0 + jl) * 64 + b];
    float iz = ps[(2 + jl) * 64 + b];
    float in = ps[(4 + jl) * 64 + b];
    if (C0) {
      ir += psE[(0 + jl) * 64 + b];
      iz += psE[(2 + jl) * 64 + b];
      in += psE[(4 + jl) * 64 + b];
    }
    float hr = ps[(6 + jl) * 64 + b];
    float hz = ps[(8 + jl) * 64 + b];
    float hn_ = ps[(10 + jl) * 64 + b];
    int j = blk * 2 + jl;
    float r = fast_sigmoid(ir + hr + bih[j] + bhh[j]);
    float z = fast_sigmoid(iz + hz + bih[Hd + j] + bhh[Hd + j]);
    float n = fast_tanh(in + bih[2 * Hd + j] + r * (hn_ + bhh[2 * Hd + j]));
    float hp = hT[j * 64 + b];
    float out = (1.f - z) * n + z * hp;
    houtT[j * 64 + b] = out;
    if (!C0) ys[((size_t)t * 64 + b) * Hd + j] = out;
  }
}

__global__ __launch_bounds__(1024, 1) void k_decoder(
    const float* __restrict__ h0_in, const int* __restrict__ vlen,
    const unsigned short* __restrict__ Wqbf, const float* __restrict__ wvp,
    const float* __restrict__ Wih0, const float* __restrict__ Whh0,
    const float* __restrict__ bih0, const float* __restrict__ bhh0,
    const float* __restrict__ Wih1, const float* __restrict__ Whh1,
    const float* __restrict__ bih1, const float* __restrict__ bhh1,
    const unsigned short* __restrict__ kpbf, const unsigned short* __restrict__ encbf,
    const float* __restrict__ embTf, int* bar, float* ctxT, float* den,
    float* h0TA, float* h0TB, float* h1TA, float* h1TB, float* ys) {
  __shared__ __align__(16) float wLDS[WTOT];               // 55296 B
  __shared__ __align__(16) unsigned short kpL[32 * 512];   // 32768 B
  __shared__ __align__(16) unsigned short encL[32 * 512];  // 32768 B
  __shared__ __align__(16) float scratch[1280];            // 5120 B
  int blk = blockIdx.x, tid = threadIdx.x;
  int lane = tid & 63;
  int w = tid >> 6;
  int battn = blk >> 2, q = blk & 3;
  int* arrive = bar;
  int* go = bar + NBLK;
  int ep = 0;

  // ---- one-time staging ----
  {
    int j0 = blk * 2;
#pragma unroll
    for (int rr = 0; rr < 6; rr++) {
      int g = rr >> 1, jl = rr & 1;
      int row = g * Hd + j0 + jl;
      const float* s0 = Wih0 + (size_t)row * 768;
      for (int k = tid; k < 768; k += 1024) wLDS[W0IH + rr * 768 + k] = s0[k];
      const float* s1 = Whh0 + (size_t)row * Hd;
      for (int k = tid; k < Hd; k += 1024) wLDS[W0HH + rr * 512 + k] = s1[k];
      const float* s2 = Wih1 + (size_t)row * Hd;
      for (int k = tid; k < Hd; k += 1024) wLDS[W1IH + rr * 512 + k] = s2[k];
      const float* s3 = Whh1 + (size_t)row * Hd;
      for (int k = tid; k < Hd; k += 1024) wLDS[W1HH + rr * 512 + k] = s3[k];
    }
    // kp/enc slices: 32 s-rows each (contiguous 32KB), as uint4
    const uint4* ksrc = (const uint4*)(kpbf + ((size_t)battn * Sd + q * 32) * Hd);
    const uint4* esrc = (const uint4*)(encbf + ((size_t)battn * Sd + q * 32) * Hd);
    uint4* kdst = (uint4*)kpL;
    uint4* edst = (uint4*)encL;
    for (int i = tid; i < 2048; i += 1024) {
      kdst[i] = ksrc[i];
      edst[i] = esrc[i];
    }
  }
  // wv -> registers
  float wvr[8];
#pragma unroll
  for (int i = 0; i < 8; i++) wvr[i] = wvp[lane * 8 + i];

  // init: h0 transpose (blocks 0..63); zero ctxT/den
  if (blk < Bd) {
    int b = blk;
    for (int k = tid; k < Hd; k += 1024) {
      h0TA[k * 64 + b] = h0_in[(0 * Bd + b) * Hd + k];
      h1TA[k * 64 + b] = h0_in[(1 * Bd + b) * Hd + k];
    }
  }
  if (tid < 128) ctxT[blk * 128 + tid] = 0.f;
  if (blk < Bd && tid == 128) den[blk] = 0.f;
  gbar(arrive, go, ++ep, blk, tid);

  for (int t = 0; t < Td; t++) {
    const float* h0prev = (t & 1) ? h0TB : h0TA;
    float* h0next = (t & 1) ? h0TA : h0TB;
    const float* h1prev = (t & 1) ? h1TB : h1TA;
    float* h1next = (t & 1) ? h1TA : h1TB;

    // ---- P_A: fused qproj + attention partial (ALL 256 blocks; b=battn) ----
    {
      int b = battn;
      float* qpL = scratch;        // [512]
      float* sc = scratch + 512;   // [32]
      // h1[b, lane*8..+8] slice -> regs (8 parallel gathers)
      float hv[8];
#pragma unroll
      for (int i = 0; i < 8; i++) hv[i] = h1prev[(lane * 8 + i) * 64 + b];
      // qproj: wave w computes rows w*32..w*32+31 from bf16 Wq (coalesced L2)
      const uint4* Wq4 = (const uint4*)Wqbf;
#pragma unroll 2
      for (int rr = 0; rr < 32; rr += 2) {
        int n0 = w * 32 + rr;
        uint4 u0 = Wq4[(size_t)n0 * 64 + lane];
        uint4 u1 = Wq4[(size_t)(n0 + 1) * 64 + lane];
        float acc0 =
            hv[0] * __uint_as_float(u0.x << 16) + hv[1] * __uint_as_float(u0.x & 0xffff0000u) +
            hv[2] * __uint_as_float(u0.y << 16) + hv[3] * __uint_as_float(u0.y & 0xffff0000u) +
            hv[4] * __uint_as_float(u0.z << 16) + hv[5] * __uint_as_float(u0.z & 0xffff0000u) +
            hv[6] * __uint_as_float(u0.w << 16) + hv[7] * __uint_as_float(u0.w & 0xffff0000u);
        float acc1 =
            hv[0] * __uint_as_float(u1.x << 16) + hv[1] * __uint_as_float(u1.x & 0xffff0000u) +
            hv[2] * __uint_as_float(u1.y << 16) + hv[3] * __uint_as_float(u1.y & 0xffff0000u) +
            hv[4] * __uint_as_float(u1.z << 16) + hv[5] * __uint_as_float(u1.z & 0xffff0000u) +
            hv[6] * __uint_as_float(u1.w << 16) + hv[7] * __uint_as_float(u1.w & 0xffff0000u);
#pragma unroll
        for (int off = 1; off < 64; off <<= 1) {
          acc0 += __shfl_xor(acc0, off);
          acc1 += __shfl_xor(acc1, off);
        }
        if (lane == 0) {
          qpL[n0] = acc0;
          qpL[n0 + 1] = acc1;
        }
      }
      __syncthreads();
      float qv[8];
#pragma unroll
      for (int i = 0; i < 8; i++) qv[i] = qpL[lane * 8 + i];
      int vl = vlen[b];
      // scores: wave w -> s_local = 2w, 2w+1; exp without max (|score|<=~9)
#pragma unroll
      for (int si = 0; si < 2; si++) {
        int sl = w * 2 + si;
        uint4 kw = *(const uint4*)&kpL[sl * 512 + lane * 8];
        float f0 = __uint_as_float(kw.x << 16);
        float f1 = __uint_as_float(kw.x & 0xffff0000u);
        float f2 = __uint_as_float(kw.y << 16);
        float f3 = __uint_as_float(kw.y & 0xffff0000u);
        float f4 = __uint_as_float(kw.z << 16);
        float f5 = __uint_as_float(kw.z & 0xffff0000u);
        float f6 = __uint_as_float(kw.w << 16);
        float f7 = __uint_as_float(kw.w & 0xffff0000u);
        float acc = wvr[0] * fast_tanh(qv[0] + f0) + wvr[1] * fast_tanh(qv[1] + f1) +
                    wvr[2] * fast_tanh(qv[2] + f2) + wvr[3] * fast_tanh(qv[3] + f3) +
                    wvr[4] * fast_tanh(qv[4] + f4) + wvr[5] * fast_tanh(qv[5] + f5) +
                    wvr[6] * fast_tanh(qv[6] + f6) + wvr[7] * fast_tanh(qv[7] + f7);
#pragma unroll
        for (int off = 1; off < 64; off <<= 1) acc += __shfl_xor(acc, off);
        if (lane == 0) {
          int s = q * 32 + sl;
          sc[sl] = (s < vl) ? __expf(acc) : 0.f;
        }
      }
      __syncthreads();
      // partial denominator
      if (tid < 32) {
        float p = sc[tid];
#pragma unroll
        for (int off = 1; off < 32; off <<= 1) p += __shfl_xor(p, off, 32);
        if (tid == 0) atomicAdd(&den[b], p);
      }
      // partial context (unnormalized) via fp32 atomics
      if (tid < 512) {
        float acc = 0.f;
#pragma unroll 8
        for (int s = 0; s < 32; s++) acc += sc[s] * bf2f(encL[s * 512 + tid]);
        atomicAdd(&ctxT[tid * 64 + battn], acc);
      }
    }
    gbar(arrive, go, ++ep, blk, tid);

    // ---- P_B: GRU cell 0 (ctx scaled by 1/den inside) ----
    cell_phase<true>(blk, tid, t, ctxT, embTf, h0prev, wLDS + W0IH, wLDS + W0HH,
                     bih0, bhh0, den, h0next, nullptr, scratch);
    gbar(arrive, go, ++ep, blk, tid);

    // ---- P_C: zero ctxT/den + GRU cell 1 ----
    if (tid < 128) ctxT[blk * 128 + tid] = 0.f;
    if (blk < Bd && tid == 128) den[blk] = 0.f;
    cell_phase<false>(blk, tid, t, h0next, nullptr, h1prev, wLDS + W1IH,
                      wLDS + W1HH, bih1, bhh1, nullptr, h1next, ys, scratch);
    gbar(arrive, go, ++ep, blk, tid);
  }
}

extern "C" void kernel_launch(void* const* d_in, const int* in_sizes, int n_in,
                              void* d_out, int out_size, void* d_ws, size_t ws_size,
                              hipStream_t stream) {
  const int* x = (const int*)d_in[0];
  const float* enc = (const float*)d_in[1];
  const float* h0 = (const float*)d_in[2];
  const int* vlen = (const int*)d_in[3];
  const float* emb = (const float*)d_in[4];
  const float* Wq = (const float*)d_in[5];
  const float* Wk = (const float*)d_in[6];
  const float* wv = (const float*)d_in[7];
  const float* W_ih0 = (const float*)d_in[8];
  const float* W_hh0 = (const float*)d_in[9];
  const float* b_ih0 = (const float*)d_in[10];
  const float* b_hh0 = (const float*)d_in[11];
  const float* W_ih1 = (const float*)d_in[12];
  const float* W_hh1 = (const float*)d_in[13];
  const float* b_ih1 = (const float*)d_in[14];
  const float* b_hh1 = (const float*)d_in[15];
  const float* Wd = (const float*)d_in[16];
  const float* bd = (const float*)d_in[17];
  float* out = (float*)d_out;

  char* p = (char*)d_ws;
  int* bar = (int*)p;
  p += 2048;
  unsigned short* kpbf = (unsigned short*)p;  // B*S*H bf16
  p += (size_t)Bd * Sd * Hd * 2;
  unsigned short* encbf = (unsigned short*)p;  // B*S*H bf16
  p += (size_t)Bd * Sd * Hd * 2;
  unsigned short* Wqbf = (unsigned short*)p;  // H*H bf16
  p += (size_t)Hd * Hd * 2;
  float* embTf = (float*)p;  // T*E*B f32
  p += (size_t)Td * Ed * Bd * 4;
  float* ctxT = (float*)p;  p += (size_t)Hd * Bd * 4;
  float* den = (float*)p;   p += 256;
  float* h0TA = (float*)p;  p += (size_t)Hd * Bd * 4;
  float* h0TB = (float*)p;  p += (size_t)Hd * Bd * 4;
  float* h1TA = (float*)p;  p += (size_t)Hd * Bd * 4;
  float* h1TB = (float*)p;  p += (size_t)Hd * Bd * 4;
  float* ys = (float*)p;    // T*B*H f32

  hipMemsetAsync(bar, 0, 2048, stream);

  // kp = enc @ Wk^T -> bf16
  k_gemm_abt<false, false, true><<<dim3(128, 8), 256, 0, stream>>>(
      enc, Wk, nullptr, kpbf, Bd * Sd, Hd, Hd);
  // enc -> bf16 copy; Wq -> bf16 copy
  long nenc = (long)Bd * Sd * Hd;
  k_tobf<<<(nenc + 1023) / 1024, 1024, 0, stream>>>(enc, encbf, nenc);
  long nwq = (long)Hd * Hd;
  k_tobf<<<(nwq + 1023) / 1024, 1024, 0, stream>>>(Wq, Wqbf, nwq);
  // embTf gather+transpose (f32)
  k_embT<<<Td, 256, 0, stream>>>(x, emb, embTf);
  // fused 64-step decoder (3 barriers/step)
  k_decoder<<<NBLK, 1024, 0, stream>>>(h0, vlen, Wqbf, wv, W_ih0, W_hh0, b_ih0,
                                       b_hh0, W_ih1, W_hh1, b_ih1, b_hh1, kpbf,
                                       encbf, embTf, bar, ctxT, den, h0TA, h0TB,
                                       h1TA, h1TB, ys);
  // logits: ys(T*B,H) @ Wd^T + bd, out[b,t,v]
  k_gemm_abt<true, true, false><<<dim3(64, 157), 256, 0, stream>>>(
      ys, Wd, bd, out, Td * Bd, Vd, Hd);
}

// Round 11
// 6928.558 us; speedup vs baseline: 1.4966x; 1.4966x over previous
//
#include <hip/hip_runtime.h>
#include <hip/hip_bf16.h>

#define Bd 64
#define Td 64
#define Sd 128
#define Hd 512
#define Ed 256
#define Vd 10000
#define NBLK 256

// LDS weight offsets (floats)
#define W0IH 0      // 6*768
#define W0HH 4608   // 6*512
#define W1IH 7680   // 6*512
#define W1HH 10752  // 6*512
#define WTOT 13824

__device__ __forceinline__ float fast_tanh(float x) {
  float e = __expf(-2.0f * fabsf(x));
  float r = (1.0f - e) / (1.0f + e);
  return copysignf(r, x);
}
__device__ __forceinline__ float fast_sigmoid(float x) {
  return 1.0f / (1.0f + __expf(-x));
}
__device__ __forceinline__ float bf2f(unsigned short u) {
  return __uint_as_float(((unsigned int)u) << 16);
}

// software grid barrier, single-stage: every block release-stores its epoch,
// then tid<256 poll ALL slots (relaxed, no per-poll cache ops), one acquire
// fence at exit. Monotonic epochs; faster blocks storing ep+1 still satisfy
// `>= ep` for laggards.
__device__ __forceinline__ void gbar(int* arrive, int ep, int blk, int tid) {
  __syncthreads();
  if (tid == 0) {
    __builtin_amdgcn_fence(__ATOMIC_RELEASE, "agent");
    __hip_atomic_store(&arrive[blk], ep, __ATOMIC_RELAXED, __HIP_MEMORY_SCOPE_AGENT);
  }
  if (tid < NBLK) {
    while (__hip_atomic_load(&arrive[tid], __ATOMIC_RELAXED,
                             __HIP_MEMORY_SCOPE_AGENT) < ep) {
      __builtin_amdgcn_s_sleep(1);
    }
  }
  __syncthreads();
  if (tid == 0) __builtin_amdgcn_fence(__ATOMIC_ACQUIRE, "agent");
  __syncthreads();
}

// C[M,N] = A[M,K] @ W[N,K]^T (+bias). SWAP: out row m=(t*64+b) -> (b*T+t).
template <bool SWAP, bool BIAS, bool OB>
__global__ void k_gemm_abt(const float* __restrict__ A, const float* __restrict__ W,
                           const float* __restrict__ bias, void* __restrict__ Cv,
                           int M, int N, int K) {
  __shared__ __align__(16) float As[16][64];
  __shared__ __align__(16) float Ws[16][64];
  int m0 = blockIdx.x * 64, n0 = blockIdx.y * 64;
  int tid = threadIdx.x;
  int tx = tid & 15, ty = tid >> 4;
  float acc[4][4] = {};
  for (int k0 = 0; k0 < K; k0 += 16) {
#pragma unroll
    for (int i = 0; i < 4; i++) {
      int e = tid + i * 256;
      int r = e >> 4, c = e & 15;
      As[c][r] = A[(long)(m0 + r) * K + k0 + c];
    }
#pragma unroll
    for (int i = 0; i < 4; i++) {
      int e = tid + i * 256;
      int r = e >> 4, c = e & 15;
      int n = n0 + r;
      Ws[c][r] = (n < N) ? W[(long)n * K + k0 + c] : 0.0f;
    }
    __syncthreads();
#pragma unroll
    for (int k = 0; k < 16; k++) {
      float a_[4], w_[4];
#pragma unroll
      for (int i = 0; i < 4; i++) a_[i] = As[k][ty * 4 + i];
#pragma unroll
      for (int j = 0; j < 4; j++) w_[j] = Ws[k][tx * 4 + j];
#pragma unroll
      for (int i = 0; i < 4; i++)
#pragma unroll
        for (int j = 0; j < 4; j++) acc[i][j] += a_[i] * w_[j];
    }
    __syncthreads();
  }
#pragma unroll
  for (int i = 0; i < 4; i++) {
    int m = m0 + ty * 4 + i;
#pragma unroll
    for (int j = 0; j < 4; j++) {
      int n = n0 + tx * 4 + j;
      if (n < N) {
        float v = acc[i][j];
        if (BIAS) v += bias[n];
        long idx;
        if (SWAP) {
          int t_ = m >> 6, b_ = m & 63;
          idx = ((long)(b_ * Td + t_)) * N + n;
        } else {
          idx = (long)m * N + n;
        }
        if (OB) {
          __hip_bfloat16 h = __float2bfloat16(v);
          ((unsigned short*)Cv)[idx] = *(unsigned short*)&h;
        } else {
          ((float*)Cv)[idx] = v;
        }
      }
    }
  }
}

// elementwise f32 -> bf16 copy
__global__ void k_tobf(const float* __restrict__ src, unsigned short* __restrict__ dst,
                       long n) {
  long i = (long)blockIdx.x * 1024 + threadIdx.x;
  if (i < n) {
    __hip_bfloat16 h = __float2bfloat16(src[i]);
    dst[i] = *(unsigned short*)&h;
  }
}

// embTf[t][e][b] = emb[x[b][t]][e]  (f32)
__global__ void k_embT(const int* __restrict__ x, const float* __restrict__ emb,
                       float* __restrict__ embTf) {
  __shared__ int rows[64];
  int t = blockIdx.x;
  if (threadIdx.x < 64) rows[threadIdx.x] = x[threadIdx.x * Td + t];
  __syncthreads();
  int e = threadIdx.x;
  for (int b = 0; b < 64; b++) {
    embTf[((long)t * Ed + e) * 64 + b] = emb[(long)rows[b] * Ed + e];
  }
}

// GRU cell phase. 12 dot-waves = 6 row-pairs x 2 K-halves: wave computes TWO
// weight rows over one 256-k half of ONE state stream (halves per-block state
// traffic vs one-row-per-wave). float4 LDS weight reads, 32 loads in flight.
// Waves 12-14 (C0 only): emb rows. Combine + nonlinearity by threads 0-127.
template <bool C0>
__device__ __forceinline__ void cell_phase(
    int blk, int tid, int t, const float* __restrict__ aT,
    const float* __restrict__ embTf, const float* __restrict__ hT,
    const float* wIH, const float* wHH, const float* __restrict__ bih,
    const float* __restrict__ bhh, const float* __restrict__ dscale,
    float* __restrict__ houtT, float* __restrict__ ys, float* scratch) {
  int lane = tid & 63;
  int w = tid >> 6;
  const int RIH = C0 ? 768 : 512;
  float* ps = scratch;          // [12 rows][2 halves][64]
  float* psE = scratch + 1536;  // [6][64]
  if (w < 12) {
    int p = w >> 1, h = w & 1;
    bool ih = p < 3;
    int g = ih ? p : p - 3;
    const float* A = (ih ? aT : hT) + h * 256 * 64;
    const float* w0;
    const float* w1;
    if (ih) {
      w0 = wIH + (size_t)(2 * g) * RIH + h * 256;
      w1 = w0 + RIH;
    } else {
      w0 = wHH + (size_t)(2 * g) * 512 + h * 256;
      w1 = w0 + 512;
    }
    float a0 = 0.f, a1 = 0.f;
#pragma unroll 8
    for (int k = 0; k < 256; k += 4) {
      float4 x0 = *(const float4*)&w0[k];
      float4 x1 = *(const float4*)&w1[k];
      float v0 = A[(k + 0) * 64 + lane];
      float v1 = A[(k + 1) * 64 + lane];
      float v2 = A[(k + 2) * 64 + lane];
      float v3 = A[(k + 3) * 64 + lane];
      a0 += v0 * x0.x + v1 * x0.y + v2 * x0.z + v3 * x0.w;
      a1 += v0 * x1.x + v1 * x1.y + v2 * x1.z + v3 * x1.w;
    }
    if (C0 && ih) {  // normalize softmax denominator (linear, per half OK)
      float inv = 1.0f / dscale[lane];
      a0 *= inv;
      a1 *= inv;
    }
    int R0 = (ih ? 0 : 6) + 2 * g;
    ps[(R0 * 2 + h) * 64 + lane] = a0;
    ps[((R0 + 1) * 2 + h) * 64 + lane] = a1;
  } else if (C0 && w < 15) {
    int r0 = (w - 12) * 2;
    const float* w0 = wIH + (size_t)r0 * 768 + 512;
    const float* w1 = wIH + (size_t)(r0 + 1) * 768 + 512;
    const float* ef = embTf + (size_t)t * Ed * 64;
    float a0 = 0.f, a1 = 0.f;
#pragma unroll 8
    for (int e = 0; e < 256; e += 4) {
      float4 x0 = *(const float4*)&w0[e];
      float4 x1 = *(const float4*)&w1[e];
      float v0 = ef[(e + 0) * 64 + lane];
      float v1 = ef[(e + 1) * 64 + lane];
      float v2 = ef[(e + 2) * 64 + lane];
      float v3 = ef[(e + 3) * 64 + lane];
      a0 += v0 * x0.x + v1 * x0.y + v2 * x0.z + v3 * x0.w;
      a1 += v0 * x1.x + v1 * x1.y + v2 * x1.z + v3 * x1.w;
    }
    psE[r0 * 64 + lane] = a0;
    psE[(r0 + 1) * 64 + lane] = a1;
  }
  __syncthreads();
  if (tid < 128) {
    int jl = tid >> 6, b = tid & 63;
#define RD(R) (ps[((R)*2 + 0) * 64 + b] + ps[((R)*2 + 1) * 64 + b])
    float ir = RD(0 + jl);
    float iz = RD(2 + jl);
    float in = RD(4 + jl);
    if (C0) {
      ir += psE[(0 + jl) * 64 + b];
      iz += psE[(2 + jl) * 64 + b];
      in += psE[(4 + jl) * 64 + b];
    }
    float hr = RD(6 + jl);
    float hz = RD(8 + jl);
    float hn_ = RD(10 + jl);
#undef RD
    int j = blk * 2 + jl;
    float r = fast_sigmoid(ir + hr + bih[j] + bhh[j]);
    float z = fast_sigmoid(iz + hz + bih[Hd + j] + bhh[Hd + j]);
    float n = fast_tanh(in + bih[2 * Hd + j] + r * (hn_ + bhh[2 * Hd + j]));
    float hp = hT[j * 64 + b];
    float out = (1.f - z) * n + z * hp;
    houtT[j * 64 + b] = out;
    if (!C0) ys[((size_t)t * 64 + b) * Hd + j] = out;
  }
}

__global__ __launch_bounds__(1024, 1) void k_decoder(
    const float* __restrict__ h0_in, const int* __restrict__ vlen,
    const float* __restrict__ Wq, const float* __restrict__ wvp,
    const float* __restrict__ Wih0, const float* __restrict__ Whh0,
    const float* __restrict__ bih0, const float* __restrict__ bhh0,
    const float* __restrict__ Wih1, const float* __restrict__ Whh1,
    const float* __restrict__ bih1, const float* __restrict__ bhh1,
    const unsigned short* __restrict__ kpbf, const unsigned short* __restrict__ encbf,
    const float* __restrict__ embTf, int* bar, float* qpN, float* ctxT,
    float* den, float* h0TA, float* h0TB, float* h1TA, float* h1TB, float* ys) {
  __shared__ __align__(16) float wLDS[WTOT];               // 55296 B
  __shared__ __align__(16) float WqL[1024];                // 4096 B
  __shared__ __align__(16) unsigned short kpL[32 * 512];   // 32768 B
  __shared__ __align__(16) unsigned short encL[32 * 512];  // 32768 B
  __shared__ __align__(16) float scratch[1920];            // 7680 B
  int blk = blockIdx.x, tid = threadIdx.x;
  int lane = tid & 63;
  int w = tid >> 6;
  int battn = blk >> 2, q = blk & 3;
  int* arrive = bar;
  int ep = 0;

  // ---- one-time staging ----
  {
    int j0 = blk * 2;
#pragma unroll
    for (int rr = 0; rr < 6; rr++) {
      int g = rr >> 1, jl = rr & 1;
      int row = g * Hd + j0 + jl;
      const float* s0 = Wih0 + (size_t)row * 768;
      for (int k = tid; k < 768; k += 1024) wLDS[W0IH + rr * 768 + k] = s0[k];
      const float* s1 = Whh0 + (size_t)row * Hd;
      for (int k = tid; k < Hd; k += 1024) wLDS[W0HH + rr * 512 + k] = s1[k];
      const float* s2 = Wih1 + (size_t)row * Hd;
      for (int k = tid; k < Hd; k += 1024) wLDS[W1IH + rr * 512 + k] = s2[k];
      const float* s3 = Whh1 + (size_t)row * Hd;
      for (int k = tid; k < Hd; k += 1024) wLDS[W1HH + rr * 512 + k] = s3[k];
    }
    // Wq rows 2blk, 2blk+1 -> LDS (f32)
    WqL[tid] = Wq[(size_t)(blk * 2 + (tid >> 9)) * Hd + (tid & 511)];
    // kp/enc slices: 32 s-rows each (contiguous 32KB), as uint4
    const uint4* ksrc = (const uint4*)(kpbf + ((size_t)battn * Sd + q * 32) * Hd);
    const uint4* esrc = (const uint4*)(encbf + ((size_t)battn * Sd + q * 32) * Hd);
    uint4* kdst = (uint4*)kpL;
    uint4* edst = (uint4*)encL;
    for (int i = tid; i < 2048; i += 1024) {
      kdst[i] = ksrc[i];
      edst[i] = esrc[i];
    }
  }
  // wv -> registers
  float wvr[8];
#pragma unroll
  for (int i = 0; i < 8; i++) wvr[i] = wvp[lane * 8 + i];

  // init: h0 transpose (blocks 0..63); zero ctxT/den
  if (blk < Bd) {
    int b = blk;
    for (int k = tid; k < Hd; k += 1024) {
      h0TA[k * 64 + b] = h0_in[(0 * Bd + b) * Hd + k];
      h1TA[k * 64 + b] = h0_in[(1 * Bd + b) * Hd + k];
    }
  }
  if (tid < 128) ctxT[blk * 128 + tid] = 0.f;
  if (blk < Bd && tid == 128) den[blk] = 0.f;
  gbar(arrive, ++ep, blk, tid);

  for (int t = 0; t < Td; t++) {
    const float* h0prev = (t & 1) ? h0TB : h0TA;
    float* h0next = (t & 1) ? h0TA : h0TB;
    const float* h1prev = (t & 1) ? h1TB : h1TA;
    float* h1next = (t & 1) ? h1TA : h1TB;

    // ---- P0: qproj, 256 blocks x 2 rows (LDS Wq); write qpN[b][n] ----
    {
      int rl = w >> 3, ks = w & 7;
      const float* qrow = &WqL[rl * 512 + ks * 64];
      const float* hp = h1prev + ks * 64 * 64;
      float acc = 0.f;
#pragma unroll 8
      for (int kk = 0; kk < 64; kk++) acc += hp[kk * 64 + lane] * qrow[kk];
      scratch[w * 64 + lane] = acc;
      __syncthreads();
      if (tid < 128) {
        int rl2 = tid >> 6, b = tid & 63;
        float s = 0.f;
#pragma unroll
        for (int qq = 0; qq < 8; qq++) s += scratch[(rl2 * 8 + qq) * 64 + b];
        qpN[(size_t)b * 512 + blk * 2 + rl2] = s;  // scattered write, fire&forget
      }
    }
    gbar(arrive, ++ep, blk, tid);

    // ---- P1: attention partial (ALL blocks; b=battn, 32 s-rows from LDS) ----
    {
      int b = battn;
      float* sc = scratch;  // [32]
      float qv[8];
      const float* qb = qpN + (size_t)b * 512 + lane * 8;  // coalesced
#pragma unroll
      for (int i = 0; i < 8; i++) qv[i] = qb[i];
      int vl = vlen[b];
#pragma unroll
      for (int si = 0; si < 2; si++) {
        int sl = w * 2 + si;
        uint4 kw = *(const uint4*)&kpL[sl * 512 + lane * 8];
        float f0 = __uint_as_float(kw.x << 16);
        float f1 = __uint_as_float(kw.x & 0xffff0000u);
        float f2 = __uint_as_float(kw.y << 16);
        float f3 = __uint_as_float(kw.y & 0xffff0000u);
        float f4 = __uint_as_float(kw.z << 16);
        float f5 = __uint_as_float(kw.z & 0xffff0000u);
        float f6 = __uint_as_float(kw.w << 16);
        float f7 = __uint_as_float(kw.w & 0xffff0000u);
        float acc = wvr[0] * fast_tanh(qv[0] + f0) + wvr[1] * fast_tanh(qv[1] + f1) +
                    wvr[2] * fast_tanh(qv[2] + f2) + wvr[3] * fast_tanh(qv[3] + f3) +
                    wvr[4] * fast_tanh(qv[4] + f4) + wvr[5] * fast_tanh(qv[5] + f5) +
                    wvr[6] * fast_tanh(qv[6] + f6) + wvr[7] * fast_tanh(qv[7] + f7);
#pragma unroll
        for (int off = 1; off < 64; off <<= 1) acc += __shfl_xor(acc, off);
        if (lane == 0) {
          int s = q * 32 + sl;
          sc[sl] = (s < vl) ? __expf(acc) : 0.f;  // no-max softmax: |score|<=~9
        }
      }
      __syncthreads();
      if (tid < 32) {
        float p2 = sc[tid];
#pragma unroll
        for (int off = 1; off < 32; off <<= 1) p2 += __shfl_xor(p2, off, 32);
        if (tid == 0) atomicAdd(&den[b], p2);
      }
      if (tid < 512) {
        float acc = 0.f;
#pragma unroll 8
        for (int s = 0; s < 32; s++) acc += sc[s] * bf2f(encL[s * 512 + tid]);
        atomicAdd(&ctxT[tid * 64 + b], acc);
      }
    }
    gbar(arrive, ++ep, blk, tid);

    // ---- P2: GRU cell 0 (ctx scaled by 1/den inside) ----
    cell_phase<true>(blk, tid, t, ctxT, embTf, h0prev, wLDS + W0IH, wLDS + W0HH,
                     bih0, bhh0, den, h0next, nullptr, scratch);
    gbar(arrive, ++ep, blk, tid);

    // ---- P3: zero ctxT/den + GRU cell 1 ----
    if (tid < 128) ctxT[blk * 128 + tid] = 0.f;
    if (blk < Bd && tid == 128) den[blk] = 0.f;
    cell_phase<false>(blk, tid, t, h0next, nullptr, h1prev, wLDS + W1IH,
                      wLDS + W1HH, bih1, bhh1, nullptr, h1next, ys, scratch);
    gbar(arrive, ++ep, blk, tid);
  }
}

extern "C" void kernel_launch(void* const* d_in, const int* in_sizes, int n_in,
                              void* d_out, int out_size, void* d_ws, size_t ws_size,
                              hipStream_t stream) {
  const int* x = (const int*)d_in[0];
  const float* enc = (const float*)d_in[1];
  const float* h0 = (const float*)d_in[2];
  const int* vlen = (const int*)d_in[3];
  const float* emb = (const float*)d_in[4];
  const float* Wq = (const float*)d_in[5];
  const float* Wk = (const float*)d_in[6];
  const float* wv = (const float*)d_in[7];
  const float* W_ih0 = (const float*)d_in[8];
  const float* W_hh0 = (const float*)d_in[9];
  const float* b_ih0 = (const float*)d_in[10];
  const float* b_hh0 = (const float*)d_in[11];
  const float* W_ih1 = (const float*)d_in[12];
  const float* W_hh1 = (const float*)d_in[13];
  const float* b_ih1 = (const float*)d_in[14];
  const float* b_hh1 = (const float*)d_in[15];
  const float* Wd = (const float*)d_in[16];
  const float* bd = (const float*)d_in[17];
  float* out = (float*)d_out;

  char* p = (char*)d_ws;
  int* bar = (int*)p;
  p += 2048;
  unsigned short* kpbf = (unsigned short*)p;  // B*S*H bf16
  p += (size_t)Bd * Sd * Hd * 2;
  unsigned short* encbf = (unsigned short*)p;  // B*S*H bf16
  p += (size_t)Bd * Sd * Hd * 2;
  float* embTf = (float*)p;  // T*E*B f32
  p += (size_t)Td * Ed * Bd * 4;
  float* qpN = (float*)p;   p += (size_t)Bd * Hd * 4;
  float* ctxT = (float*)p;  p += (size_t)Hd * Bd * 4;
  float* den = (float*)p;   p += 256;
  float* h0TA = (float*)p;  p += (size_t)Hd * Bd * 4;
  float* h0TB = (float*)p;  p += (size_t)Hd * Bd * 4;
  float* h1TA = (float*)p;  p += (size_t)Hd * Bd * 4;
  float* h1TB = (float*)p;  p += (size_t)Hd * Bd * 4;
  float* ys = (float*)p;    // T*B*H f32

  hipMemsetAsync(bar, 0, 2048, stream);

  // kp = enc @ Wk^T -> bf16
  k_gemm_abt<false, false, true><<<dim3(128, 8), 256, 0, stream>>>(
      enc, Wk, nullptr, kpbf, Bd * Sd, Hd, Hd);
  // enc -> bf16 copy
  long nenc = (long)Bd * Sd * Hd;
  k_tobf<<<(nenc + 1023) / 1024, 1024, 0, stream>>>(enc, encbf, nenc);
  // embTf gather+transpose (f32)
  k_embT<<<Td, 256, 0, stream>>>(x, emb, embTf);
  // fused 64-step decoder (4 barriers/step)
  k_decoder<<<NBLK, 1024, 0, stream>>>(h0, vlen, Wq, wv, W_ih0, W_hh0, b_ih0,
                                       b_hh0, W_ih1, W_hh1, b_ih1, b_hh1, kpbf,
                                       encbf, embTf, bar, qpN, ctxT, den, h0TA,
                                       h0TB, h1TA, h1TB, ys);
  // logits: ys(T*B,H) @ Wd^T + bd, out[b,t,v]
  k_gemm_abt<true, true, false><<<dim3(64, 157), 256, 0, stream>>>(
      ys, Wd, bd, out, Td * Bd, Vd, Hd);
}

// Round 12
// 5005.474 us; speedup vs baseline: 2.0716x; 1.3842x over previous
//
#include <hip/hip_runtime.h>
#include <hip/hip_bf16.h>

#define Bd 64
#define Td 64
#define Sd 128
#define Hd 512
#define Ed 256
#define Vd 10000
#define NBLK 256

// LDS weight offsets (floats)
#define W0IH 0      // 6*768
#define W0HH 4608   // 6*512
#define W1IH 7680   // 6*512
#define W1HH 10752  // 6*512
#define WTOT 13824

__device__ __forceinline__ float fast_tanh(float x) {
  float e = __expf(-2.0f * fabsf(x));
  float r = (1.0f - e) / (1.0f + e);
  return copysignf(r, x);
}
__device__ __forceinline__ float fast_sigmoid(float x) {
  return 1.0f / (1.0f + __expf(-x));
}
__device__ __forceinline__ float bf2f(unsigned short u) {
  return __uint_as_float(((unsigned int)u) << 16);
}
__device__ __forceinline__ void st_llc(float* p, float v) {
  __hip_atomic_store(p, v, __ATOMIC_RELAXED, __HIP_MEMORY_SCOPE_AGENT);
}

// software grid barrier, wbl2-free: ALL cross-block state is written with
// agent-scope atomic stores (write-through to LLC), so no release writeback is
// needed — __syncthreads() drains each wave's vmcnt (stores complete at LLC)
// before the arrive store. Two-stage: block0 aggregates (64 lanes x 4 slots,
// light LLC traffic), others poll one `go` line. One acquire inv at exit.
__device__ __forceinline__ void gbar(int* arrive, int* go, int ep, int blk, int tid) {
  __syncthreads();  // drains vmcnt of all waves -> prior stores visible at LLC
  if (tid == 0)
    __hip_atomic_store(&arrive[blk], ep, __ATOMIC_RELAXED, __HIP_MEMORY_SCOPE_AGENT);
  if (blk == 0) {
    if (tid < 64) {
      for (;;) {
        int a0 = __hip_atomic_load(&arrive[tid], __ATOMIC_RELAXED,
                                   __HIP_MEMORY_SCOPE_AGENT);
        int a1 = __hip_atomic_load(&arrive[tid + 64], __ATOMIC_RELAXED,
                                   __HIP_MEMORY_SCOPE_AGENT);
        int a2 = __hip_atomic_load(&arrive[tid + 128], __ATOMIC_RELAXED,
                                   __HIP_MEMORY_SCOPE_AGENT);
        int a3 = __hip_atomic_load(&arrive[tid + 192], __ATOMIC_RELAXED,
                                   __HIP_MEMORY_SCOPE_AGENT);
        if (a0 >= ep && a1 >= ep && a2 >= ep && a3 >= ep) break;
        __builtin_amdgcn_s_sleep(2);
      }
    }
    __syncthreads();
    if (tid == 0)
      __hip_atomic_store(go, ep, __ATOMIC_RELAXED, __HIP_MEMORY_SCOPE_AGENT);
  }
  if (tid == 0) {
    while (__hip_atomic_load(go, __ATOMIC_RELAXED, __HIP_MEMORY_SCOPE_AGENT) < ep) {
      __builtin_amdgcn_s_sleep(1);
    }
    __builtin_amdgcn_fence(__ATOMIC_ACQUIRE, "agent");  // single L2 inv
  }
  __syncthreads();
}

// C[M,N] = A[M,K] @ W[N,K]^T (+bias). SWAP: out row m=(t*64+b) -> (b*T+t).
template <bool SWAP, bool BIAS, bool OB>
__global__ void k_gemm_abt(const float* __restrict__ A, const float* __restrict__ W,
                           const float* __restrict__ bias, void* __restrict__ Cv,
                           int M, int N, int K) {
  __shared__ __align__(16) float As[16][64];
  __shared__ __align__(16) float Ws[16][64];
  int m0 = blockIdx.x * 64, n0 = blockIdx.y * 64;
  int tid = threadIdx.x;
  int tx = tid & 15, ty = tid >> 4;
  float acc[4][4] = {};
  for (int k0 = 0; k0 < K; k0 += 16) {
#pragma unroll
    for (int i = 0; i < 4; i++) {
      int e = tid + i * 256;
      int r = e >> 4, c = e & 15;
      As[c][r] = A[(long)(m0 + r) * K + k0 + c];
    }
#pragma unroll
    for (int i = 0; i < 4; i++) {
      int e = tid + i * 256;
      int r = e >> 4, c = e & 15;
      int n = n0 + r;
      Ws[c][r] = (n < N) ? W[(long)n * K + k0 + c] : 0.0f;
    }
    __syncthreads();
#pragma unroll
    for (int k = 0; k < 16; k++) {
      float a_[4], w_[4];
#pragma unroll
      for (int i = 0; i < 4; i++) a_[i] = As[k][ty * 4 + i];
#pragma unroll
      for (int j = 0; j < 4; j++) w_[j] = Ws[k][tx * 4 + j];
#pragma unroll
      for (int i = 0; i < 4; i++)
#pragma unroll
        for (int j = 0; j < 4; j++) acc[i][j] += a_[i] * w_[j];
    }
    __syncthreads();
  }
#pragma unroll
  for (int i = 0; i < 4; i++) {
    int m = m0 + ty * 4 + i;
#pragma unroll
    for (int j = 0; j < 4; j++) {
      int n = n0 + tx * 4 + j;
      if (n < N) {
        float v = acc[i][j];
        if (BIAS) v += bias[n];
        long idx;
        if (SWAP) {
          int t_ = m >> 6, b_ = m & 63;
          idx = ((long)(b_ * Td + t_)) * N + n;
        } else {
          idx = (long)m * N + n;
        }
        if (OB) {
          __hip_bfloat16 h = __float2bfloat16(v);
          ((unsigned short*)Cv)[idx] = *(unsigned short*)&h;
        } else {
          ((float*)Cv)[idx] = v;
        }
      }
    }
  }
}

// elementwise f32 -> bf16 copy
__global__ void k_tobf(const float* __restrict__ src, unsigned short* __restrict__ dst,
                       long n) {
  long i = (long)blockIdx.x * 1024 + threadIdx.x;
  if (i < n) {
    __hip_bfloat16 h = __float2bfloat16(src[i]);
    dst[i] = *(unsigned short*)&h;
  }
}

// embTf[t][e][b] = emb[x[b][t]][e]  (f32)
__global__ void k_embT(const int* __restrict__ x, const float* __restrict__ emb,
                       float* __restrict__ embTf) {
  __shared__ int rows[64];
  int t = blockIdx.x;
  if (threadIdx.x < 64) rows[threadIdx.x] = x[threadIdx.x * Td + t];
  __syncthreads();
  int e = threadIdx.x;
  for (int b = 0; b < 64; b++) {
    embTf[((long)t * Ed + e) * 64 + b] = emb[(long)rows[b] * Ed + e];
  }
}

// GRU cell phase. 12 dot-waves = 6 row-pairs x 2 K-halves. float4 LDS weight
// reads, 32 loads in flight. Waves 12-14 (C0 only): emb rows. Combine +
// nonlinearity by threads 0-127; h-out written via LLC atomic store.
template <bool C0>
__device__ __forceinline__ void cell_phase(
    int blk, int tid, int t, const float* __restrict__ aT,
    const float* __restrict__ embTf, const float* __restrict__ hT,
    const float* wIH, const float* wHH, const float* __restrict__ bih,
    const float* __restrict__ bhh, const float* __restrict__ dscale,
    float* __restrict__ houtT, float* __restrict__ ys, float* scratch) {
  int lane = tid & 63;
  int w = tid >> 6;
  const int RIH = C0 ? 768 : 512;
  float* ps = scratch;          // [12 rows][2 halves][64]
  float* psE = scratch + 1536;  // [6][64]
  if (w < 12) {
    int p = w >> 1, h = w & 1;
    bool ih = p < 3;
    int g = ih ? p : p - 3;
    const float* A = (ih ? aT : hT) + h * 256 * 64;
    const float* w0;
    const float* w1;
    if (ih) {
      w0 = wIH + (size_t)(2 * g) * RIH + h * 256;
      w1 = w0 + RIH;
    } else {
      w0 = wHH + (size_t)(2 * g) * 512 + h * 256;
      w1 = w0 + 512;
    }
    float a0 = 0.f, a1 = 0.f;
#pragma unroll 8
    for (int k = 0; k < 256; k += 4) {
      float4 x0 = *(const float4*)&w0[k];
      float4 x1 = *(const float4*)&w1[k];
      float v0 = A[(k + 0) * 64 + lane];
      float v1 = A[(k + 1) * 64 + lane];
      float v2 = A[(k + 2) * 64 + lane];
      float v3 = A[(k + 3) * 64 + lane];
      a0 += v0 * x0.x + v1 * x0.y + v2 * x0.z + v3 * x0.w;
      a1 += v0 * x1.x + v1 * x1.y + v2 * x1.z + v3 * x1.w;
    }
    if (C0 && ih) {
      float inv = 1.0f / dscale[lane];
      a0 *= inv;
      a1 *= inv;
    }
    int R0 = (ih ? 0 : 6) + 2 * g;
    ps[(R0 * 2 + h) * 64 + lane] = a0;
    ps[((R0 + 1) * 2 + h) * 64 + lane] = a1;
  } else if (C0 && w < 15) {
    int r0 = (w - 12) * 2;
    const float* w0 = wIH + (size_t)r0 * 768 + 512;
    const float* w1 = wIH + (size_t)(r0 + 1) * 768 + 512;
    const float* ef = embTf + (size_t)t * Ed * 64;
    float a0 = 0.f, a1 = 0.f;
#pragma unroll 8
    for (int e = 0; e < 256; e += 4) {
      float4 x0 = *(const float4*)&w0[e];
      float4 x1 = *(const float4*)&w1[e];
      float v0 = ef[(e + 0) * 64 + lane];
      float v1 = ef[(e + 1) * 64 + lane];
      float v2 = ef[(e + 2) * 64 + lane];
      float v3 = ef[(e + 3) * 64 + lane];
      a0 += v0 * x0.x + v1 * x0.y + v2 * x0.z + v3 * x0.w;
      a1 += v0 * x1.x + v1 * x1.y + v2 * x1.z + v3 * x1.w;
    }
    psE[r0 * 64 + lane] = a0;
    psE[(r0 + 1) * 64 + lane] = a1;
  }
  __syncthreads();
  if (tid < 128) {
    int jl = tid >> 6, b = tid & 63;
#define RD(R) (ps[((R)*2 + 0) * 64 + b] + ps[((R)*2 + 1) * 64 + b])
    float ir = RD(0 + jl);
    float iz = RD(2 + jl);
    float in = RD(4 + jl);
    if (C0) {
      ir += psE[(0 + jl) * 64 + b];
      iz += psE[(2 + jl) * 64 + b];
      in += psE[(4 + jl) * 64 + b];
    }
    float hr = RD(6 + jl);
    float hz = RD(8 + jl);
    float hn_ = RD(10 + jl);
#undef RD
    int j = blk * 2 + jl;
    float r = fast_sigmoid(ir + hr + bih[j] + bhh[j]);
    float z = fast_sigmoid(iz + hz + bih[Hd + j] + bhh[Hd + j]);
    float n = fast_tanh(in + bih[2 * Hd + j] + r * (hn_ + bhh[2 * Hd + j]));
    float hp = hT[j * 64 + b];
    float out = (1.f - z) * n + z * hp;
    st_llc(&houtT[j * 64 + b], out);
    if (!C0) ys[((size_t)t * 64 + b) * Hd + j] = out;
  }
}

__global__ __launch_bounds__(1024, 1) void k_decoder(
    const float* __restrict__ h0_in, const int* __restrict__ vlen,
    const float* __restrict__ Wq, const float* __restrict__ wvp,
    const float* __restrict__ Wih0, const float* __restrict__ Whh0,
    const float* __restrict__ bih0, const float* __restrict__ bhh0,
    const float* __restrict__ Wih1, const float* __restrict__ Whh1,
    const float* __restrict__ bih1, const float* __restrict__ bhh1,
    const unsigned short* __restrict__ kpbf, const unsigned short* __restrict__ encbf,
    const float* __restrict__ embTf, int* bar, float* qpN, float* ctxT,
    float* den, float* h0TA, float* h0TB, float* h1TA, float* h1TB, float* ys) {
  __shared__ __align__(16) float wLDS[WTOT];               // 55296 B
  __shared__ __align__(16) float WqL[1024];                // 4096 B
  __shared__ __align__(16) unsigned short kpL[32 * 512];   // 32768 B
  __shared__ __align__(16) unsigned short encL[32 * 512];  // 32768 B
  __shared__ __align__(16) float scratch[1920];            // 7680 B
  int blk = blockIdx.x, tid = threadIdx.x;
  int lane = tid & 63;
  int w = tid >> 6;
  int battn = blk >> 2, q = blk & 3;
  int* arrive = bar;
  int* go = bar + NBLK;
  int ep = 0;

  // ---- one-time staging ----
  {
    int j0 = blk * 2;
#pragma unroll
    for (int rr = 0; rr < 6; rr++) {
      int g = rr >> 1, jl = rr & 1;
      int row = g * Hd + j0 + jl;
      const float* s0 = Wih0 + (size_t)row * 768;
      for (int k = tid; k < 768; k += 1024) wLDS[W0IH + rr * 768 + k] = s0[k];
      const float* s1 = Whh0 + (size_t)row * Hd;
      for (int k = tid; k < Hd; k += 1024) wLDS[W0HH + rr * 512 + k] = s1[k];
      const float* s2 = Wih1 + (size_t)row * Hd;
      for (int k = tid; k < Hd; k += 1024) wLDS[W1IH + rr * 512 + k] = s2[k];
      const float* s3 = Whh1 + (size_t)row * Hd;
      for (int k = tid; k < Hd; k += 1024) wLDS[W1HH + rr * 512 + k] = s3[k];
    }
    // Wq rows 2blk, 2blk+1 -> LDS (f32)
    WqL[tid] = Wq[(size_t)(blk * 2 + (tid >> 9)) * Hd + (tid & 511)];
    // kp/enc slices: 32 s-rows each (contiguous 32KB), as uint4
    const uint4* ksrc = (const uint4*)(kpbf + ((size_t)battn * Sd + q * 32) * Hd);
    const uint4* esrc = (const uint4*)(encbf + ((size_t)battn * Sd + q * 32) * Hd);
    uint4* kdst = (uint4*)kpL;
    uint4* edst = (uint4*)encL;
    for (int i = tid; i < 2048; i += 1024) {
      kdst[i] = ksrc[i];
      edst[i] = esrc[i];
    }
  }
  // wv -> registers
  float wvr[8];
#pragma unroll
  for (int i = 0; i < 8; i++) wvr[i] = wvp[lane * 8 + i];

  // init: h0 transpose (blocks 0..63) via LLC stores; zero ctxT/den
  if (blk < Bd) {
    int b = blk;
    for (int k = tid; k < Hd; k += 1024) {
      st_llc(&h0TA[k * 64 + b], h0_in[(0 * Bd + b) * Hd + k]);
      st_llc(&h1TA[k * 64 + b], h0_in[(1 * Bd + b) * Hd + k]);
    }
  }
  if (tid < 128) st_llc(&ctxT[blk * 128 + tid], 0.f);
  if (blk < Bd && tid == 128) st_llc(&den[blk], 0.f);
  gbar(arrive, go, ++ep, blk, tid);

  for (int t = 0; t < Td; t++) {
    const float* h0prev = (t & 1) ? h0TB : h0TA;
    float* h0next = (t & 1) ? h0TA : h0TB;
    const float* h1prev = (t & 1) ? h1TB : h1TA;
    float* h1next = (t & 1) ? h1TA : h1TB;

    // ---- P0: qproj, 256 blocks x 2 rows (LDS Wq); write qpN[b][n] ----
    {
      int rl = w >> 3, ks = w & 7;
      const float* qrow = &WqL[rl * 512 + ks * 64];
      const float* hp = h1prev + ks * 64 * 64;
      float acc = 0.f;
#pragma unroll 8
      for (int kk = 0; kk < 64; kk++) acc += hp[kk * 64 + lane] * qrow[kk];
      scratch[w * 64 + lane] = acc;
      __syncthreads();
      if (tid < 128) {
        int rl2 = tid >> 6, b = tid & 63;
        float s = 0.f;
#pragma unroll
        for (int qq = 0; qq < 8; qq++) s += scratch[(rl2 * 8 + qq) * 64 + b];
        st_llc(&qpN[(size_t)b * 512 + blk * 2 + rl2], s);
      }
    }
    gbar(arrive, go, ++ep, blk, tid);

    // ---- P1: attention partial (ALL blocks; b=battn, 32 s-rows from LDS) ----
    {
      int b = battn;
      float* sc = scratch;  // [32]
      float qv[8];
      const float* qb = qpN + (size_t)b * 512 + lane * 8;  // coalesced
#pragma unroll
      for (int i = 0; i < 8; i++) qv[i] = qb[i];
      int vl = vlen[b];
#pragma unroll
      for (int si = 0; si < 2; si++) {
        int sl = w * 2 + si;
        uint4 kw = *(const uint4*)&kpL[sl * 512 + lane * 8];
        float f0 = __uint_as_float(kw.x << 16);
        float f1 = __uint_as_float(kw.x & 0xffff0000u);
        float f2 = __uint_as_float(kw.y << 16);
        float f3 = __uint_as_float(kw.y & 0xffff0000u);
        float f4 = __uint_as_float(kw.z << 16);
        float f5 = __uint_as_float(kw.z & 0xffff0000u);
        float f6 = __uint_as_float(kw.w << 16);
        float f7 = __uint_as_float(kw.w & 0xffff0000u);
        float acc = wvr[0] * fast_tanh(qv[0] + f0) + wvr[1] * fast_tanh(qv[1] + f1) +
                    wvr[2] * fast_tanh(qv[2] + f2) + wvr[3] * fast_tanh(qv[3] + f3) +
                    wvr[4] * fast_tanh(qv[4] + f4) + wvr[5] * fast_tanh(qv[5] + f5) +
                    wvr[6] * fast_tanh(qv[6] + f6) + wvr[7] * fast_tanh(qv[7] + f7);
#pragma unroll
        for (int off = 1; off < 64; off <<= 1) acc += __shfl_xor(acc, off);
        if (lane == 0) {
          int s = q * 32 + sl;
          sc[sl] = (s < vl) ? __expf(acc) : 0.f;  // no-max softmax: |score|<=~9
        }
      }
      __syncthreads();
      if (tid < 32) {
        float p2 = sc[tid];
#pragma unroll
        for (int off = 1; off < 32; off <<= 1) p2 += __shfl_xor(p2, off, 32);
        if (tid == 0) atomicAdd(&den[b], p2);
      }
      if (tid < 512) {
        float acc = 0.f;
#pragma unroll 8
        for (int s = 0; s < 32; s++) acc += sc[s] * bf2f(encL[s * 512 + tid]);
        atomicAdd(&ctxT[tid * 64 + b], acc);
      }
    }
    gbar(arrive, go, ++ep, blk, tid);

    // ---- P2: GRU cell 0 (ctx scaled by 1/den inside) ----
    cell_phase<true>(blk, tid, t, ctxT, embTf, h0prev, wLDS + W0IH, wLDS + W0HH,
                     bih0, bhh0, den, h0next, nullptr, scratch);
    gbar(arrive, go, ++ep, blk, tid);

    // ---- P3: zero ctxT/den + GRU cell 1 ----
    if (tid < 128) st_llc(&ctxT[blk * 128 + tid], 0.f);
    if (blk < Bd && tid == 128) st_llc(&den[blk], 0.f);
    cell_phase<false>(blk, tid, t, h0next, nullptr, h1prev, wLDS + W1IH,
                      wLDS + W1HH, bih1, bhh1, nullptr, h1next, ys, scratch);
    gbar(arrive, go, ++ep, blk, tid);
  }
}

extern "C" void kernel_launch(void* const* d_in, const int* in_sizes, int n_in,
                              void* d_out, int out_size, void* d_ws, size_t ws_size,
                              hipStream_t stream) {
  const int* x = (const int*)d_in[0];
  const float* enc = (const float*)d_in[1];
  const float* h0 = (const float*)d_in[2];
  const int* vlen = (const int*)d_in[3];
  const float* emb = (const float*)d_in[4];
  const float* Wq = (const float*)d_in[5];
  const float* Wk = (const float*)d_in[6];
  const float* wv = (const float*)d_in[7];
  const float* W_ih0 = (const float*)d_in[8];
  const float* W_hh0 = (const float*)d_in[9];
  const float* b_ih0 = (const float*)d_in[10];
  const float* b_hh0 = (const float*)d_in[11];
  const float* W_ih1 = (const float*)d_in[12];
  const float* W_hh1 = (const float*)d_in[13];
  const float* b_ih1 = (const float*)d_in[14];
  const float* b_hh1 = (const float*)d_in[15];
  const float* Wd = (const float*)d_in[16];
  const float* bd = (const float*)d_in[17];
  float* out = (float*)d_out;

  char* p = (char*)d_ws;
  int* bar = (int*)p;
  p += 2048;
  unsigned short* kpbf = (unsigned short*)p;  // B*S*H bf16
  p += (size_t)Bd * Sd * Hd * 2;
  unsigned short* encbf = (unsigned short*)p;  // B*S*H bf16
  p += (size_t)Bd * Sd * Hd * 2;
  float* embTf = (float*)p;  // T*E*B f32
  p += (size_t)Td * Ed * Bd * 4;
  float* qpN = (float*)p;   p += (size_t)Bd * Hd * 4;
  float* ctxT = (float*)p;  p += (size_t)Hd * Bd * 4;
  float* den = (float*)p;   p += 256;
  float* h0TA = (float*)p;  p += (size_t)Hd * Bd * 4;
  float* h0TB = (float*)p;  p += (size_t)Hd * Bd * 4;
  float* h1TA = (float*)p;  p += (size_t)Hd * Bd * 4;
  float* h1TB = (float*)p;  p += (size_t)Hd * Bd * 4;
  float* ys = (float*)p;    // T*B*H f32

  hipMemsetAsync(bar, 0, 2048, stream);

  // kp = enc @ Wk^T -> bf16
  k_gemm_abt<false, false, true><<<dim3(128, 8), 256, 0, stream>>>(
      enc, Wk, nullptr, kpbf, Bd * Sd, Hd, Hd);
  // enc -> bf16 copy
  long nenc = (long)Bd * Sd * Hd;
  k_tobf<<<(nenc + 1023) / 1024, 1024, 0, stream>>>(enc, encbf, nenc);
  // embTf gather+transpose (f32)
  k_embT<<<Td, 256, 0, stream>>>(x, emb, embTf);
  // fused 64-step decoder (4 barriers/step)
  k_decoder<<<NBLK, 1024, 0, stream>>>(h0, vlen, Wq, wv, W_ih0, W_hh0, b_ih0,
                                       b_hh0, W_ih1, W_hh1, b_ih1, b_hh1, kpbf,
                                       encbf, embTf, bar, qpN, ctxT, den, h0TA,
                                       h0TB, h1TA, h1TB, ys);
  // logits: ys(T*B,H) @ Wd^T + bd, out[b,t,v]
  k_gemm_abt<true, true, false><<<dim3(64, 157), 256, 0, stream>>>(
      ys, Wd, bd, out, Td * Bd, Vd, Hd);
}

// Round 13
// 4207.960 us; speedup vs baseline: 2.4643x; 1.1895x over previous
//
#include <hip/hip_runtime.h>
#include <hip/hip_bf16.h>

#define Bd 64
#define Td 64
#define Sd 128
#define Hd 512
#define Ed 256
#define Vd 10000
#define NBLK 256

#define W0IH 0      // 6*768
#define W0HH 4608   // 6*512
#define W1IH 7680   // 6*512
#define W1HH 10752  // 6*512
#define WTOT 13824

typedef __attribute__((ext_vector_type(8))) short bf16x8;
typedef __attribute__((ext_vector_type(4))) float f32x4;

__device__ __forceinline__ float fast_tanh(float x) {
  float e = __expf(-2.0f * fabsf(x));
  float r = (1.0f - e) / (1.0f + e);
  return copysignf(r, x);
}
__device__ __forceinline__ float fast_sigmoid(float x) {
  return 1.0f / (1.0f + __expf(-x));
}
__device__ __forceinline__ float bf2f(unsigned short u) {
  return __uint_as_float(((unsigned int)u) << 16);
}
__device__ __forceinline__ void st_llc(float* p, float v) {
  __hip_atomic_store(p, v, __ATOMIC_RELAXED, __HIP_MEMORY_SCOPE_AGENT);
}
// k-quad state layout: element (k, b) lives at (k>>2)*256 + b*4 + (k&3)
__device__ __forceinline__ int q4(int k, int b) {
  return (k >> 2) * 256 + b * 4 + (k & 3);
}

// wbl2-free grid barrier (r12): relaxed arrive/go + single acquire inv.
__device__ __forceinline__ void gbar(int* arrive, int* go, int ep, int blk, int tid) {
  __syncthreads();
  if (tid == 0)
    __hip_atomic_store(&arrive[blk], ep, __ATOMIC_RELAXED, __HIP_MEMORY_SCOPE_AGENT);
  if (blk == 0) {
    if (tid < 64) {
      for (;;) {
        int a0 = __hip_atomic_load(&arrive[tid], __ATOMIC_RELAXED,
                                   __HIP_MEMORY_SCOPE_AGENT);
        int a1 = __hip_atomic_load(&arrive[tid + 64], __ATOMIC_RELAXED,
                                   __HIP_MEMORY_SCOPE_AGENT);
        int a2 = __hip_atomic_load(&arrive[tid + 128], __ATOMIC_RELAXED,
                                   __HIP_MEMORY_SCOPE_AGENT);
        int a3 = __hip_atomic_load(&arrive[tid + 192], __ATOMIC_RELAXED,
                                   __HIP_MEMORY_SCOPE_AGENT);
        if (a0 >= ep && a1 >= ep && a2 >= ep && a3 >= ep) break;
        __builtin_amdgcn_s_sleep(2);
      }
    }
    __syncthreads();
    if (tid == 0)
      __hip_atomic_store(go, ep, __ATOMIC_RELAXED, __HIP_MEMORY_SCOPE_AGENT);
  }
  if (tid == 0) {
    while (__hip_atomic_load(go, __ATOMIC_RELAXED, __HIP_MEMORY_SCOPE_AGENT) < ep) {
      __builtin_amdgcn_s_sleep(1);
    }
    __builtin_amdgcn_fence(__ATOMIC_ACQUIRE, "agent");
  }
  __syncthreads();
}

// fp32 tiled GEMM (used only for kp prep). C[M,N] = A[M,K] @ W[N,K]^T, bf16 out.
__global__ void k_gemm_kp(const float* __restrict__ A, const float* __restrict__ W,
                          unsigned short* __restrict__ C, int M, int N, int K) {
  __shared__ __align__(16) float As[16][64];
  __shared__ __align__(16) float Ws[16][64];
  int m0 = blockIdx.x * 64, n0 = blockIdx.y * 64;
  int tid = threadIdx.x;
  int tx = tid & 15, ty = tid >> 4;
  float acc[4][4] = {};
  for (int k0 = 0; k0 < K; k0 += 16) {
#pragma unroll
    for (int i = 0; i < 4; i++) {
      int e = tid + i * 256;
      int r = e >> 4, c = e & 15;
      As[c][r] = A[(long)(m0 + r) * K + k0 + c];
      Ws[c][r] = W[(long)(n0 + r) * K + k0 + c];
    }
    __syncthreads();
#pragma unroll
    for (int k = 0; k < 16; k++) {
      float a_[4], w_[4];
#pragma unroll
      for (int i = 0; i < 4; i++) a_[i] = As[k][ty * 4 + i];
#pragma unroll
      for (int j = 0; j < 4; j++) w_[j] = Ws[k][tx * 4 + j];
#pragma unroll
      for (int i = 0; i < 4; i++)
#pragma unroll
        for (int j = 0; j < 4; j++) acc[i][j] += a_[i] * w_[j];
    }
    __syncthreads();
  }
#pragma unroll
  for (int i = 0; i < 4; i++)
#pragma unroll
    for (int j = 0; j < 4; j++) {
      __hip_bfloat16 h = __float2bfloat16(acc[i][j]);
      C[(long)(m0 + ty * 4 + i) * N + n0 + tx * 4 + j] = *(unsigned short*)&h;
    }
}

// bf16 MFMA logits GEMM: out[b*T+t][n] = ys[t*64+b][:] . Wd[n][:] + bd[n]
__global__ __launch_bounds__(256) void k_logits(
    const unsigned short* __restrict__ ysbf, const unsigned short* __restrict__ Wdbf,
    const float* __restrict__ bd, float* __restrict__ out, int N) {
  int m0 = blockIdx.x * 64, n0 = blockIdx.y * 64;
  int w = threadIdx.x >> 6, lane = threadIdx.x & 63;
  int row = lane & 15, kg = lane >> 4;
  int mw = m0 + w * 16;
  f32x4 acc[4] = {};
  const unsigned short* Arow = ysbf + (size_t)(mw + row) * 512 + kg * 8;
  for (int k0 = 0; k0 < 512; k0 += 32) {
    bf16x8 af = *(const bf16x8*)(Arow + k0);
#pragma unroll
    for (int nn = 0; nn < 4; nn++) {
      int ncol = n0 + nn * 16 + row;
      bf16x8 bfv = {};
      if (ncol < N) bfv = *(const bf16x8*)(Wdbf + (size_t)ncol * 512 + k0 + kg * 8);
      acc[nn] = __builtin_amdgcn_mfma_f32_16x16x32_bf16(af, bfv, acc[nn], 0, 0, 0);
    }
  }
#pragma unroll
  for (int nn = 0; nn < 4; nn++) {
    int ncol = n0 + nn * 16 + row;
    if (ncol < N) {
      float bv = bd[ncol];
#pragma unroll
      for (int r = 0; r < 4; r++) {
        int mm = mw + kg * 4 + r;
        int t_ = mm >> 6, b_ = mm & 63;
        out[((size_t)(b_ * Td + t_)) * N + ncol] = acc[nn][r] + bv;
      }
    }
  }
}

// elementwise f32 -> bf16 copy
__global__ void k_tobf(const float* __restrict__ src, unsigned short* __restrict__ dst,
                       long n) {
  long i = (long)blockIdx.x * 1024 + threadIdx.x;
  if (i < n) {
    __hip_bfloat16 h = __float2bfloat16(src[i]);
    dst[i] = *(unsigned short*)&h;
  }
}

// embTf: k-quad layout per t: (e,b) -> t*16384 + (e>>2)*256 + b*4 + (e&3)
__global__ void k_embT(const int* __restrict__ x, const float* __restrict__ emb,
                       float* __restrict__ embTf) {
  __shared__ int rows[64];
  int t = blockIdx.x;
  if (threadIdx.x < 64) rows[threadIdx.x] = x[threadIdx.x * Td + t];
  __syncthreads();
  int e = threadIdx.x;
  for (int b = 0; b < 64; b++) {
    embTf[(size_t)t * 16384 + q4(e, b)] = emb[(long)rows[b] * Ed + e];
  }
}

// GRU cell phase; state in k-quad layout -> float4 loads (16B/lane coalesced).
// 12 dot-waves = 6 row-pairs x 2 K-halves; waves 12-14 (C0): emb rows.
template <bool C0>
__device__ __forceinline__ void cell_phase(
    int blk, int tid, int t, const float* __restrict__ aT,
    const float* __restrict__ embTf, const float* __restrict__ hT,
    const float* wIH, const float* wHH, const float* __restrict__ bih,
    const float* __restrict__ bhh, const float* __restrict__ dscale,
    float* __restrict__ houtT, unsigned short* __restrict__ ysbf, float* scratch) {
  int lane = tid & 63;
  int w = tid >> 6;
  const int RIH = C0 ? 768 : 512;
  float* ps = scratch;          // [12 rows][2 halves][64]
  float* psE = scratch + 1536;  // [6][64]
  if (w < 12) {
    int p = w >> 1, h = w & 1;
    bool ih = p < 3;
    int g = ih ? p : p - 3;
    const float* A = (ih ? aT : hT) + h * 64 * 256;  // half h: k-quads h*64..
    const float* w0;
    const float* w1;
    if (ih) {
      w0 = wIH + (size_t)(2 * g) * RIH + h * 256;
      w1 = w0 + RIH;
    } else {
      w0 = wHH + (size_t)(2 * g) * 512 + h * 256;
      w1 = w0 + 512;
    }
    float a0 = 0.f, a1 = 0.f;
#pragma unroll 16
    for (int k = 0; k < 256; k += 4) {
      float4 x0 = *(const float4*)&w0[k];
      float4 x1 = *(const float4*)&w1[k];
      float4 av = *(const float4*)&A[(k >> 2) * 256 + lane * 4];
      a0 += av.x * x0.x + av.y * x0.y + av.z * x0.z + av.w * x0.w;
      a1 += av.x * x1.x + av.y * x1.y + av.z * x1.z + av.w * x1.w;
    }
    if (C0 && ih) {
      float inv = 1.0f / dscale[lane];
      a0 *= inv;
      a1 *= inv;
    }
    int R0 = (ih ? 0 : 6) + 2 * g;
    ps[(R0 * 2 + h) * 64 + lane] = a0;
    ps[((R0 + 1) * 2 + h) * 64 + lane] = a1;
  } else if (C0 && w < 15) {
    int r0 = (w - 12) * 2;
    const float* w0 = wIH + (size_t)r0 * 768 + 512;
    const float* w1 = wIH + (size_t)(r0 + 1) * 768 + 512;
    const float* ef = embTf + (size_t)t * 16384;
    float a0 = 0.f, a1 = 0.f;
#pragma unroll 16
    for (int e = 0; e < 256; e += 4) {
      float4 x0 = *(const float4*)&w0[e];
      float4 x1 = *(const float4*)&w1[e];
      float4 ev = *(const float4*)&ef[(e >> 2) * 256 + lane * 4];
      a0 += ev.x * x0.x + ev.y * x0.y + ev.z * x0.z + ev.w * x0.w;
      a1 += ev.x * x1.x + ev.y * x1.y + ev.z * x1.z + ev.w * x1.w;
    }
    psE[r0 * 64 + lane] = a0;
    psE[(r0 + 1) * 64 + lane] = a1;
  }
  __syncthreads();
  if (tid < 128) {
    int jl = tid >> 6, b = tid & 63;
#define RD(R) (ps[((R)*2 + 0) * 64 + b] + ps[((R)*2 + 1) * 64 + b])
    float ir = RD(0 + jl);
    float iz = RD(2 + jl);
    float in = RD(4 + jl);
    if (C0) {
      ir += psE[(0 + jl) * 64 + b];
      iz += psE[(2 + jl) * 64 + b];
      in += psE[(4 + jl) * 64 + b];
    }
    float hr = RD(6 + jl);
    float hz = RD(8 + jl);
    float hn_ = RD(10 + jl);
#undef RD
    int j = blk * 2 + jl;
    float r = fast_sigmoid(ir + hr + bih[j] + bhh[j]);
    float z = fast_sigmoid(iz + hz + bih[Hd + j] + bhh[Hd + j]);
    float n = fast_tanh(in + bih[2 * Hd + j] + r * (hn_ + bhh[2 * Hd + j]));
    float hp = hT[q4(j, b)];
    float out = (1.f - z) * n + z * hp;
    st_llc(&houtT[q4(j, b)], out);
    if (!C0) {
      __hip_bfloat16 hb = __float2bfloat16(out);
      ysbf[((size_t)t * 64 + b) * 512 + j] = *(unsigned short*)&hb;
    }
  }
}

__global__ __launch_bounds__(1024, 1) void k_decoder(
    const float* __restrict__ h0_in, const int* __restrict__ vlen,
    const float* __restrict__ Wq, const float* __restrict__ wvp,
    const float* __restrict__ Wih0, const float* __restrict__ Whh0,
    const float* __restrict__ bih0, const float* __restrict__ bhh0,
    const float* __restrict__ Wih1, const float* __restrict__ Whh1,
    const float* __restrict__ bih1, const float* __restrict__ bhh1,
    const unsigned short* __restrict__ kpbf, const unsigned short* __restrict__ encbf,
    const float* __restrict__ embTf, int* bar, float* qpN, float* ctxT,
    float* den, float* h0TA, float* h0TB, float* h1TA, float* h1TB,
    unsigned short* ysbf) {
  __shared__ __align__(16) float wLDS[WTOT];               // 55296 B
  __shared__ __align__(16) float WqL[1024];                // 4096 B
  __shared__ __align__(16) unsigned short kpL[32 * 512];   // 32768 B
  __shared__ __align__(16) unsigned short encL[32 * 512];  // 32768 B
  __shared__ __align__(16) float scratch[1920];            // 7680 B
  int blk = blockIdx.x, tid = threadIdx.x;
  int lane = tid & 63;
  int w = tid >> 6;
  int battn = blk >> 2, q = blk & 3;
  int* arrive = bar;
  int* go = bar + NBLK;
  int ep = 0;

  // ---- one-time staging ----
  {
    int j0 = blk * 2;
#pragma unroll
    for (int rr = 0; rr < 6; rr++) {
      int g = rr >> 1, jl = rr & 1;
      int row = g * Hd + j0 + jl;
      const float* s0 = Wih0 + (size_t)row * 768;
      for (int k = tid; k < 768; k += 1024) wLDS[W0IH + rr * 768 + k] = s0[k];
      const float* s1 = Whh0 + (size_t)row * Hd;
      for (int k = tid; k < Hd; k += 1024) wLDS[W0HH + rr * 512 + k] = s1[k];
      const float* s2 = Wih1 + (size_t)row * Hd;
      for (int k = tid; k < Hd; k += 1024) wLDS[W1IH + rr * 512 + k] = s2[k];
      const float* s3 = Whh1 + (size_t)row * Hd;
      for (int k = tid; k < Hd; k += 1024) wLDS[W1HH + rr * 512 + k] = s3[k];
    }
    WqL[tid] = Wq[(size_t)(blk * 2 + (tid >> 9)) * Hd + (tid & 511)];
    const uint4* ksrc = (const uint4*)(kpbf + ((size_t)battn * Sd + q * 32) * Hd);
    const uint4* esrc = (const uint4*)(encbf + ((size_t)battn * Sd + q * 32) * Hd);
    uint4* kdst = (uint4*)kpL;
    uint4* edst = (uint4*)encL;
    for (int i = tid; i < 2048; i += 1024) {
      kdst[i] = ksrc[i];
      edst[i] = esrc[i];
    }
  }
  float wvr[8];
#pragma unroll
  for (int i = 0; i < 8; i++) wvr[i] = wvp[lane * 8 + i];

  // init: h0 transpose into k-quad buffers; zero ctxT/den
  if (blk < Bd) {
    int b = blk;
    for (int k = tid; k < Hd; k += 1024) {
      st_llc(&h0TA[q4(k, b)], h0_in[(0 * Bd + b) * Hd + k]);
      st_llc(&h1TA[q4(k, b)], h0_in[(1 * Bd + b) * Hd + k]);
    }
  }
  if (tid < 128) st_llc(&ctxT[blk * 128 + tid], 0.f);
  if (blk < Bd && tid == 128) st_llc(&den[blk], 0.f);
  gbar(arrive, go, ++ep, blk, tid);

  for (int t = 0; t < Td; t++) {
    const float* h0prev = (t & 1) ? h0TB : h0TA;
    float* h0next = (t & 1) ? h0TA : h0TB;
    const float* h1prev = (t & 1) ? h1TB : h1TA;
    float* h1next = (t & 1) ? h1TA : h1TB;

    // ---- P0: qproj, 256 blocks x 2 rows; h1 read as k-quad float4 ----
    {
      int rl = w >> 3, ks = w & 7;
      const float* qrow = &WqL[rl * 512 + ks * 64];
      const float* hp4 = h1prev + (ks * 16) * 256 + lane * 4;
      float acc = 0.f;
#pragma unroll
      for (int kk = 0; kk < 64; kk += 4) {
        float4 hv = *(const float4*)&hp4[(kk >> 2) * 256];
        acc += hv.x * qrow[kk] + hv.y * qrow[kk + 1] + hv.z * qrow[kk + 2] +
               hv.w * qrow[kk + 3];
      }
      scratch[w * 64 + lane] = acc;
      __syncthreads();
      if (tid < 128) {
        int rl2 = tid >> 6, b = tid & 63;
        float s = 0.f;
#pragma unroll
        for (int qq = 0; qq < 8; qq++) s += scratch[(rl2 * 8 + qq) * 64 + b];
        st_llc(&qpN[(size_t)b * 512 + blk * 2 + rl2], s);
      }
    }
    gbar(arrive, go, ++ep, blk, tid);

    // ---- P1: attention partial (b=battn, 32 s-rows from LDS) ----
    {
      int b = battn;
      float* sc = scratch;  // [32]
      float qv[8];
      const float* qb = qpN + (size_t)b * 512 + lane * 8;
#pragma unroll
      for (int i = 0; i < 8; i++) qv[i] = qb[i];
      int vl = vlen[b];
#pragma unroll
      for (int si = 0; si < 2; si++) {
        int sl = w * 2 + si;
        uint4 kw = *(const uint4*)&kpL[sl * 512 + lane * 8];
        float f0 = __uint_as_float(kw.x << 16);
        float f1 = __uint_as_float(kw.x & 0xffff0000u);
        float f2 = __uint_as_float(kw.y << 16);
        float f3 = __uint_as_float(kw.y & 0xffff0000u);
        float f4 = __uint_as_float(kw.z << 16);
        float f5 = __uint_as_float(kw.z & 0xffff0000u);
        float f6 = __uint_as_float(kw.w << 16);
        float f7 = __uint_as_float(kw.w & 0xffff0000u);
        float acc = wvr[0] * fast_tanh(qv[0] + f0) + wvr[1] * fast_tanh(qv[1] + f1) +
                    wvr[2] * fast_tanh(qv[2] + f2) + wvr[3] * fast_tanh(qv[3] + f3) +
                    wvr[4] * fast_tanh(qv[4] + f4) + wvr[5] * fast_tanh(qv[5] + f5) +
                    wvr[6] * fast_tanh(qv[6] + f6) + wvr[7] * fast_tanh(qv[7] + f7);
#pragma unroll
        for (int off = 1; off < 64; off <<= 1) acc += __shfl_xor(acc, off);
        if (lane == 0) {
          int s = q * 32 + sl;
          sc[sl] = (s < vl) ? __expf(acc) : 0.f;  // no-max softmax: |score|<=~9
        }
      }
      __syncthreads();
      if (tid < 32) {
        float p2 = sc[tid];
#pragma unroll
        for (int off = 1; off < 32; off <<= 1) p2 += __shfl_xor(p2, off, 32);
        if (tid == 0) atomicAdd(&den[b], p2);
      }
      if (tid < 512) {
        float acc = 0.f;
#pragma unroll 8
        for (int s = 0; s < 32; s++) acc += sc[s] * bf2f(encL[s * 512 + tid]);
        atomicAdd(&ctxT[q4(tid, b)], acc);
      }
    }
    gbar(arrive, go, ++ep, blk, tid);

    // ---- P2: GRU cell 0 ----
    cell_phase<true>(blk, tid, t, ctxT, embTf, h0prev, wLDS + W0IH, wLDS + W0HH,
                     bih0, bhh0, den, h0next, nullptr, scratch);
    gbar(arrive, go, ++ep, blk, tid);

    // ---- P3: zero ctxT/den + GRU cell 1 ----
    if (tid < 128) st_llc(&ctxT[blk * 128 + tid], 0.f);
    if (blk < Bd && tid == 128) st_llc(&den[blk], 0.f);
    cell_phase<false>(blk, tid, t, h0next, nullptr, h1prev, wLDS + W1IH,
                      wLDS + W1HH, bih1, bhh1, nullptr, h1next, ysbf, scratch);
    gbar(arrive, go, ++ep, blk, tid);
  }
}

extern "C" void kernel_launch(void* const* d_in, const int* in_sizes, int n_in,
                              void* d_out, int out_size, void* d_ws, size_t ws_size,
                              hipStream_t stream) {
  const int* x = (const int*)d_in[0];
  const float* enc = (const float*)d_in[1];
  const float* h0 = (const float*)d_in[2];
  const int* vlen = (const int*)d_in[3];
  const float* emb = (const float*)d_in[4];
  const float* Wq = (const float*)d_in[5];
  const float* Wk = (const float*)d_in[6];
  const float* wv = (const float*)d_in[7];
  const float* W_ih0 = (const float*)d_in[8];
  const float* W_hh0 = (const float*)d_in[9];
  const float* b_ih0 = (const float*)d_in[10];
  const float* b_hh0 = (const float*)d_in[11];
  const float* W_ih1 = (const float*)d_in[12];
  const float* W_hh1 = (const float*)d_in[13];
  const float* b_ih1 = (const float*)d_in[14];
  const float* b_hh1 = (const float*)d_in[15];
  const float* Wd = (const float*)d_in[16];
  const float* bd = (const float*)d_in[17];
  float* out = (float*)d_out;

  char* p = (char*)d_ws;
  int* bar = (int*)p;
  p += 2048;
  unsigned short* kpbf = (unsigned short*)p;   // B*S*H bf16
  p += (size_t)Bd * Sd * Hd * 2;
  unsigned short* encbf = (unsigned short*)p;  // B*S*H bf16
  p += (size_t)Bd * Sd * Hd * 2;
  unsigned short* Wdbf = (unsigned short*)p;   // V*H bf16
  p += (size_t)Vd * Hd * 2;
  unsigned short* ysbf = (unsigned short*)p;   // T*B*H bf16
  p += (size_t)Td * Bd * Hd * 2;
  float* embTf = (float*)p;  // T*E*B f32 (k-quad)
  p += (size_t)Td * Ed * Bd * 4;
  float* qpN = (float*)p;   p += (size_t)Bd * Hd * 4;
  float* ctxT = (float*)p;  p += (size_t)Hd * Bd * 4;
  float* den = (float*)p;   p += 256;
  float* h0TA = (float*)p;  p += (size_t)Hd * Bd * 4;
  float* h0TB = (float*)p;  p += (size_t)Hd * Bd * 4;
  float* h1TA = (float*)p;  p += (size_t)Hd * Bd * 4;
  float* h1TB = (float*)p;

  hipMemsetAsync(bar, 0, 2048, stream);

  // kp = enc @ Wk^T -> bf16
  k_gemm_kp<<<dim3(128, 8), 256, 0, stream>>>(enc, Wk, kpbf, Bd * Sd, Hd, Hd);
  // enc, Wd -> bf16
  long nenc = (long)Bd * Sd * Hd;
  k_tobf<<<(nenc + 1023) / 1024, 1024, 0, stream>>>(enc, encbf, nenc);
  long nwd = (long)Vd * Hd;
  k_tobf<<<(nwd + 1023) / 1024, 1024, 0, stream>>>(Wd, Wdbf, nwd);
  // embTf gather+transpose (f32, k-quad)
  k_embT<<<Td, 256, 0, stream>>>(x, emb, embTf);
  // fused 64-step decoder
  k_decoder<<<NBLK, 1024, 0, stream>>>(h0, vlen, Wq, wv, W_ih0, W_hh0, b_ih0,
                                       b_hh0, W_ih1, W_hh1, b_ih1, b_hh1, kpbf,
                                       encbf, embTf, bar, qpN, ctxT, den, h0TA,
                                       h0TB, h1TA, h1TB, ysbf);
  // logits: bf16 MFMA GEMM
  k_logits<<<dim3(64, 157), 256, 0, stream>>>(ysbf, Wdbf, bd, out, Vd);
}